// Round 11
// baseline (706.390 us; speedup 1.0000x reference)
//
#include <hip/hip_runtime.h>
#include <math.h>
#include <stdint.h>

#define G_ 32000
#define E_ 256
#define K_ 8
#define D_ 6
#define B_ 4
#define L_ 512
#define M_ 64
#define KN_ 4
#define STEP_ 0.05f
#define BL_ (B_ * L_)   // 2048
#define KE_ (K_ * E_)   // 2048
#define NSPLIT_ 100
#define GCH_ 5

typedef __attribute__((ext_vector_type(8))) short short8;
typedef __attribute__((ext_vector_type(4))) float f32x4;
typedef __attribute__((ext_vector_type(4))) short short4v;

__device__ __forceinline__ short f2bf(float f) {
  unsigned u = __builtin_bit_cast(unsigned, f);
  unsigned r = (u + 0x7fffu + ((u >> 16) & 1u)) >> 16;
  return (short)r;
}
__device__ __forceinline__ float bf2f(short h) {
  return __builtin_bit_cast(float, ((unsigned)(unsigned short)h) << 16);
}

__device__ __forceinline__ void gload16(const void* g, void* l) {
  __builtin_amdgcn_global_load_lds(
      reinterpret_cast<const __attribute__((address_space(1))) void*>(
          reinterpret_cast<uintptr_t>(g)),
      reinterpret_cast<__attribute__((address_space(3))) void*>(
          reinterpret_cast<uintptr_t>(l)),
      16, 0, 0);
}

// ---------------- reduction helpers ----------------
__device__ __forceinline__ float wsum(float v) {
#pragma unroll
  for (int o = 32; o > 0; o >>= 1) v += __shfl_xor(v, o, 64);
  return v;
}
__device__ __forceinline__ float wmaxr(float v) {
#pragma unroll
  for (int o = 32; o > 0; o >>= 1) v = fmaxf(v, __shfl_xor(v, o, 64));
  return v;
}
__device__ __forceinline__ float block_sum(float v, float* sm) {
  v = wsum(v);
  int wid = threadIdx.x >> 6, lane = threadIdx.x & 63;
  if (lane == 0) sm[wid] = v;
  __syncthreads();
  float r = sm[0] + sm[1] + sm[2] + sm[3];
  __syncthreads();
  return r;
}
__device__ __forceinline__ float block_max(float v, float* sm) {
  v = wmaxr(v);
  int wid = threadIdx.x >> 6, lane = threadIdx.x & 63;
  if (lane == 0) sm[wid] = v;
  __syncthreads();
  float r = fmaxf(fmaxf(sm[0], sm[1]), fmaxf(sm[2], sm[3]));
  __syncthreads();
  return r;
}

// ---------------- 128x64 MFMA GEMM (1-D grid, XCD-swizzled) ----------------
// BF32: B operand is fp32 (N,K) read direct from input weights; converted to
// bf16 during LDS staging (reg-staged, swizzled ds_write matching the reads).
template <bool RELU, bool OBF, bool BF32>
__global__ __launch_bounds__(256) void mg128x64_k(
    const short* __restrict__ A, const void* __restrict__ Bv,
    void* __restrict__ Cg, int Kd, int lda, int ldb, int ldc) {
  __shared__ short As[128 * 64];
  __shared__ short Bs[64 * 64];
  int bid = blockIdx.x;
  int wgid = (bid & 7) * 64 + (bid >> 3);  // 512 blocks, 8 XCDs
  int m0 = (wgid & 15) * 128, n0 = (wgid >> 4) * 64;
  int t = threadIdx.x, w = t >> 6, l = t & 63;
  int l16 = l & 15, qd = l >> 4, hi8 = qd * 8;
  int wr_ = w >> 1, wc_ = w & 1;
  int sr = l >> 3;
  int scol = ((l & 7) * 8) ^ (sr << 3);
  f32x4 acc[4][2];
#pragma unroll
  for (int i = 0; i < 4; i++)
#pragma unroll
    for (int j = 0; j < 2; j++) acc[i][j] = {0.f, 0.f, 0.f, 0.f};

  for (int k0 = 0; k0 < Kd; k0 += 64) {
    __syncthreads();
#pragma unroll
    for (int c = 0; c < 4; c++) {
      int sub = w * 4 + c;
      int r = sub * 8 + sr;
      gload16(A + (long)(m0 + r) * lda + k0 + scol, &As[sub * 512]);
    }
    if (BF32) {
      const float* Bf = (const float*)Bv;
      int row = t >> 2, seg = (t & 3) * 16;
      const float4* src = (const float4*)(Bf + (long)(n0 + row) * ldb + k0 + seg);
      float4 v0 = src[0], v1 = src[1], v2 = src[2], v3 = src[3];
      short8 o0 = {f2bf(v0.x), f2bf(v0.y), f2bf(v0.z), f2bf(v0.w),
                   f2bf(v1.x), f2bf(v1.y), f2bf(v1.z), f2bf(v1.w)};
      short8 o1 = {f2bf(v2.x), f2bf(v2.y), f2bf(v2.z), f2bf(v2.w),
                   f2bf(v3.x), f2bf(v3.y), f2bf(v3.z), f2bf(v3.w)};
      int base = row * 64 + seg;
      int sw = (row & 7) << 3;
      *(short8*)&Bs[base ^ sw] = o0;
      *(short8*)&Bs[(base + 8) ^ sw] = o1;
    } else {
      const short* B = (const short*)Bv;
#pragma unroll
      for (int c = 0; c < 2; c++) {
        int sub = w * 2 + c;
        int r = sub * 8 + sr;
        gload16(B + (long)(n0 + r) * ldb + k0 + scol, &Bs[sub * 512]);
      }
    }
    __syncthreads();
#pragma unroll
    for (int ks = 0; ks < 2; ks++) {
      short8 af[4], bf[2];
#pragma unroll
      for (int rf = 0; rf < 4; rf++) {
        int row = wr_ * 64 + rf * 16 + l16;
        af[rf] = *(const short8*)&As[(row * 64 + ks * 32 + hi8) ^ ((row & 7) << 3)];
      }
#pragma unroll
      for (int cf = 0; cf < 2; cf++) {
        int row = wc_ * 32 + cf * 16 + l16;
        bf[cf] = *(const short8*)&Bs[(row * 64 + ks * 32 + hi8) ^ ((row & 7) << 3)];
      }
#pragma unroll
      for (int rf = 0; rf < 4; rf++)
#pragma unroll
        for (int cf = 0; cf < 2; cf++)
          acc[rf][cf] = __builtin_amdgcn_mfma_f32_16x16x32_bf16(
              af[rf], bf[cf], acc[rf][cf], 0, 0, 0);
    }
  }
#pragma unroll
  for (int rf = 0; rf < 4; rf++) {
#pragma unroll
    for (int cf = 0; cf < 2; cf++) {
      int col = n0 + wc_ * 32 + cf * 16 + l16;
#pragma unroll
      for (int j = 0; j < 4; j++) {
        int row = m0 + wr_ * 64 + rf * 16 + qd * 4 + j;
        float v = acc[rf][cf][j];
        if (RELU) v = fmaxf(v, 0.f);
        long idx = (long)row * ldc + col;
        if (OBF) ((short*)Cg)[idx] = f2bf(v);
        else ((float*)Cg)[idx] = v;
      }
    }
  }
}

// ---------------- 64x64 MFMA GEMM, split-K to fp32 partials ----------------
__global__ __launch_bounds__(256) void mg64sk_k(
    const short* __restrict__ A, const short* __restrict__ B,
    float* __restrict__ P, int Klen, int lda, int ldb, int ldc, long pstride) {
  __shared__ short As[64 * 64];
  __shared__ short Bs[64 * 64];
  int z = blockIdx.z;
  int kbase = z * Klen;
  int m0 = blockIdx.y * 64, n0 = blockIdx.x * 64;
  int t = threadIdx.x, w = t >> 6, l = t & 63;
  int l16 = l & 15, qd = l >> 4, hi8 = qd * 8;
  int wr_ = w >> 1, wc_ = w & 1;
  int sr = l >> 3;
  int scol = ((l & 7) * 8) ^ (sr << 3);
  f32x4 acc[2][2];
#pragma unroll
  for (int i = 0; i < 2; i++)
#pragma unroll
    for (int j = 0; j < 2; j++) acc[i][j] = {0.f, 0.f, 0.f, 0.f};

  for (int k0 = 0; k0 < Klen; k0 += 64) {
    __syncthreads();
#pragma unroll
    for (int c = 0; c < 2; c++) {
      int sub = w * 2 + c;
      int r = sub * 8 + sr;
      gload16(A + (long)(m0 + r) * lda + kbase + k0 + scol, &As[sub * 512]);
      gload16(B + (long)(n0 + r) * ldb + kbase + k0 + scol, &Bs[sub * 512]);
    }
    __syncthreads();
#pragma unroll
    for (int ks = 0; ks < 2; ks++) {
      short8 af[2], bf[2];
#pragma unroll
      for (int rf = 0; rf < 2; rf++) {
        int row = wr_ * 32 + rf * 16 + l16;
        af[rf] = *(const short8*)&As[(row * 64 + ks * 32 + hi8) ^ ((row & 7) << 3)];
      }
#pragma unroll
      for (int cf = 0; cf < 2; cf++) {
        int row = wc_ * 32 + cf * 16 + l16;
        bf[cf] = *(const short8*)&Bs[(row * 64 + ks * 32 + hi8) ^ ((row & 7) << 3)];
      }
#pragma unroll
      for (int rf = 0; rf < 2; rf++)
#pragma unroll
        for (int cf = 0; cf < 2; cf++)
          acc[rf][cf] = __builtin_amdgcn_mfma_f32_16x16x32_bf16(
              af[rf], bf[cf], acc[rf][cf], 0, 0, 0);
    }
  }
  float* Pz = P + z * pstride;
#pragma unroll
  for (int rf = 0; rf < 2; rf++) {
#pragma unroll
    for (int cf = 0; cf < 2; cf++) {
      int col = n0 + wc_ * 32 + cf * 16 + l16;
#pragma unroll
      for (int j = 0; j < 4; j++) {
        int row = m0 + wr_ * 32 + rf * 16 + qd * 4 + j;
        Pz[(long)row * ldc + col] = acc[rf][cf][j];
      }
    }
  }
}

// ---------------- 64x64 MFMA GEMM, bf16 out, batched, opt bias ----------------
template <bool BIAS>
__global__ __launch_bounds__(256) void mgh_k(
    const short* __restrict__ Ag, const short* __restrict__ Bg,
    short* __restrict__ Cg, const float* __restrict__ bias, int Kd, int lda,
    int ldb, int ldc, long sA, long sB, long sC) {
  __shared__ short As[64 * 64];
  __shared__ short Bs[64 * 64];
  int z = blockIdx.z;
  const short* A = Ag + z * sA;
  const short* B = Bg + z * sB;
  short* C = Cg + z * sC;
  int m0 = blockIdx.y * 64, n0 = blockIdx.x * 64;
  int t = threadIdx.x, w = t >> 6, l = t & 63;
  int l16 = l & 15, qd = l >> 4, hi8 = qd * 8;
  int wr_ = w >> 1, wc_ = w & 1;
  int sr = l >> 3;
  int scol = ((l & 7) * 8) ^ (sr << 3);
  f32x4 acc[2][2];
#pragma unroll
  for (int i = 0; i < 2; i++)
#pragma unroll
    for (int j = 0; j < 2; j++) acc[i][j] = {0.f, 0.f, 0.f, 0.f};

  for (int k0 = 0; k0 < Kd; k0 += 64) {
    __syncthreads();
#pragma unroll
    for (int c = 0; c < 2; c++) {
      int sub = w * 2 + c;
      int r = sub * 8 + sr;
      gload16(A + (long)(m0 + r) * lda + k0 + scol, &As[sub * 512]);
      gload16(B + (long)(n0 + r) * ldb + k0 + scol, &Bs[sub * 512]);
    }
    __syncthreads();
#pragma unroll
    for (int ks = 0; ks < 2; ks++) {
      short8 af[2], bf[2];
#pragma unroll
      for (int rf = 0; rf < 2; rf++) {
        int row = wr_ * 32 + rf * 16 + l16;
        af[rf] = *(const short8*)&As[(row * 64 + ks * 32 + hi8) ^ ((row & 7) << 3)];
      }
#pragma unroll
      for (int cf = 0; cf < 2; cf++) {
        int row = wc_ * 32 + cf * 16 + l16;
        bf[cf] = *(const short8*)&Bs[(row * 64 + ks * 32 + hi8) ^ ((row & 7) << 3)];
      }
#pragma unroll
      for (int rf = 0; rf < 2; rf++)
#pragma unroll
        for (int cf = 0; cf < 2; cf++)
          acc[rf][cf] = __builtin_amdgcn_mfma_f32_16x16x32_bf16(
              af[rf], bf[cf], acc[rf][cf], 0, 0, 0);
    }
  }
#pragma unroll
  for (int rf = 0; rf < 2; rf++) {
#pragma unroll
    for (int cf = 0; cf < 2; cf++) {
      int col = n0 + wc_ * 32 + cf * 16 + l16;
      float bv = BIAS ? bias[col] : 0.f;
#pragma unroll
      for (int j = 0; j < 4; j++) {
        int row = m0 + wr_ * 32 + rf * 16 + qd * 4 + j;
        C[(long)row * ldc + col] = f2bf(acc[rf][cf][j] + bv);
      }
    }
  }
}

// ---------------- transition pair (roll, 64x64 tiles) ----------------
__global__ __launch_bounds__(256) void tpair_k(
    const short* __restrict__ xsa_bf, const short* __restrict__ wtT,
    const short* __restrict__ wcb, short* __restrict__ T) {
  __shared__ short As[64 * 64];
  __shared__ short Bs[64 * 64];
  int z = blockIdx.z;
  const short* Bb = z ? wcb : wtT;
  int rollv = z ? -1 : 1;
  int m0 = blockIdx.y * 64, n0 = blockIdx.x * 64;
  int t = threadIdx.x, w = t >> 6, l = t & 63;
  int l16 = l & 15, qd = l >> 4, hi8 = qd * 8;
  int wr_ = w >> 1, wc_ = w & 1;
  int sr = l >> 3;
  int scol = ((l & 7) * 8) ^ (sr << 3);
  f32x4 acc[2][2];
#pragma unroll
  for (int i = 0; i < 2; i++)
#pragma unroll
    for (int j = 0; j < 2; j++) acc[i][j] = {0.f, 0.f, 0.f, 0.f};
  for (int k0 = 0; k0 < E_; k0 += 64) {
    __syncthreads();
#pragma unroll
    for (int c = 0; c < 2; c++) {
      int sub = w * 2 + c;
      int r = sub * 8 + sr;
      int gr = m0 + r;
      int bb = gr >> 9, pp = gr & (L_ - 1);
      gr = (bb << 9) | ((pp - rollv + L_) & (L_ - 1));
      gload16(xsa_bf + (long)gr * E_ + k0 + scol, &As[sub * 512]);
      gload16(Bb + (long)(n0 + r) * E_ + k0 + scol, &Bs[sub * 512]);
    }
    __syncthreads();
#pragma unroll
    for (int ks = 0; ks < 2; ks++) {
      short8 af[2], bf[2];
#pragma unroll
      for (int rf = 0; rf < 2; rf++) {
        int row = wr_ * 32 + rf * 16 + l16;
        af[rf] = *(const short8*)&As[(row * 64 + ks * 32 + hi8) ^ ((row & 7) << 3)];
      }
#pragma unroll
      for (int cf = 0; cf < 2; cf++) {
        int row = wc_ * 32 + cf * 16 + l16;
        bf[cf] = *(const short8*)&Bs[(row * 64 + ks * 32 + hi8) ^ ((row & 7) << 3)];
      }
#pragma unroll
      for (int rf = 0; rf < 2; rf++)
#pragma unroll
        for (int cf = 0; cf < 2; cf++)
          acc[rf][cf] = __builtin_amdgcn_mfma_f32_16x16x32_bf16(
              af[rf], bf[cf], acc[rf][cf], 0, 0, 0);
    }
  }
#pragma unroll
  for (int rf = 0; rf < 2; rf++) {
#pragma unroll
    for (int cf = 0; cf < 2; cf++) {
      int col = n0 + wc_ * 32 + cf * 16 + l16;
#pragma unroll
      for (int j = 0; j < 4; j++) {
        int row = m0 + wr_ * 32 + rf * 16 + qd * 4 + j;
        T[(long)row * 512 + z * 256 + col] = f2bf(fmaxf(acc[rf][cf][j], 0.f));
      }
    }
  }
}

// ---------------- flash attention v3 + setprio ----------------
__global__ __launch_bounds__(512, 2) void flash3_k(
    const short* __restrict__ q_bf, const short* __restrict__ xsa_bf,
    const short* __restrict__ xsaT_bf, short* __restrict__ y_bf) {
  __shared__ short smem[69888];
  float* Obuf = (float*)smem;
  float* mst = (float*)&smem[69632];
  float* lst = mst + 64;
  int q0 = blockIdx.x * 64, hk = blockIdx.y, b = blockIdx.z;
  int t = threadIdx.x, w = t >> 6, l = t & 63;
  int l16 = l & 15, qd = l >> 4, hi8 = qd * 8;
  int qb = w & 3, half = w >> 2;
  const float scale = 0.0625f;

  short8 qf[8];
  {
    const short* qrow =
        q_bf + (long)(b * L_ + q0 + qb * 16 + l16) * KE_ + hk * 256;
#pragma unroll
    for (int ks = 0; ks < 8; ks++)
      qf[ks] = *(const short8*)(qrow + ks * 32 + hi8);
  }
  f32x4 acc_o[16];
#pragma unroll
  for (int i = 0; i < 16; i++) acc_o[i] = {0.f, 0.f, 0.f, 0.f};
  float mreg[4], lreg[4];
#pragma unroll
  for (int j = 0; j < 4; j++) { mreg[j] = -1e30f; lreg[j] = 0.f; }

  auto STAGE = [&](int nbuf, int it) {
#pragma unroll
    for (int c = 0; c < 4; c++) {
      int ch = w * 4 + c, hh = ch >> 4, rp = ch & 15;
      int row = rp * 2 + (l >> 5);
      int colsw = ((l & 31) * 8) ^ ((row & 7) << 3);
      gload16(xsa_bf + (long)(b * L_ + hh * 256 + it * 32 + row) * E_ + colsw,
              &smem[(nbuf * 2 + hh) * 8192 + rp * 512]);
    }
#pragma unroll
    for (int c = 0; c < 4; c++) {
      int ch = w * 4 + c, hh = ch >> 4, rg = ch & 15;
      int er = rg * 16 + (l >> 2);
      int col = (l & 3) * 8;
      gload16(xsaT_bf + (long)(b * E_ + er) * L_ + hh * 256 + it * 32 + col,
              &smem[32768 + (nbuf * 2 + hh) * 8192 + rg * 512]);
    }
  };

  STAGE(0, 0);
  __syncthreads();
  int cur = 0;
  for (int it = 0; it < 8; it++) {
    if (it < 7) STAGE(cur ^ 1, it + 1);
    const short* Kb = &smem[(cur * 2 + half) * 8192];
    const short* Vb = &smem[32768 + (cur * 2 + half) * 8192];
    short* Pw = &smem[65536 + w * 512];
    f32x4 s4[2];
    s4[0] = {0.f, 0.f, 0.f, 0.f};
    s4[1] = {0.f, 0.f, 0.f, 0.f};
    __builtin_amdgcn_s_setprio(1);
#pragma unroll
    for (int ks = 0; ks < 8; ks++) {
#pragma unroll
      for (int cf = 0; cf < 2; cf++) {
        int row = cf * 16 + l16;
        short8 kb = *(const short8*)&Kb[row * 256 +
                                        ((ks * 32 + hi8) ^ ((row & 7) << 3))];
        s4[cf] = __builtin_amdgcn_mfma_f32_16x16x32_bf16(qf[ks], kb, s4[cf], 0, 0, 0);
      }
    }
    __builtin_amdgcn_s_setprio(0);
    float alpha[4];
#pragma unroll
    for (int j = 0; j < 4; j++) {
      float v0 = s4[0][j] * scale, v1 = s4[1][j] * scale;
      float rmax = fmaxf(v0, v1);
#pragma unroll
      for (int mk = 1; mk <= 8; mk <<= 1) rmax = fmaxf(rmax, __shfl_xor(rmax, mk, 64));
      float mn = fmaxf(mreg[j], rmax);
      float p0 = __expf(v0 - mn), p1 = __expf(v1 - mn);
      float ps = p0 + p1;
#pragma unroll
      for (int mk = 1; mk <= 8; mk <<= 1) ps += __shfl_xor(ps, mk, 64);
      alpha[j] = __expf(mreg[j] - mn);
      lreg[j] = lreg[j] * alpha[j] + ps;
      mreg[j] = mn;
      int r = qd * 4 + j;
      Pw[r * 32 + l16] = f2bf(p0);
      Pw[r * 32 + 16 + l16] = f2bf(p1);
    }
#pragma unroll
    for (int cfo = 0; cfo < 16; cfo++)
#pragma unroll
      for (int j = 0; j < 4; j++) acc_o[cfo][j] *= alpha[j];
    short8 pa = *(const short8*)&Pw[l16 * 32 + hi8];
    __builtin_amdgcn_s_setprio(1);
#pragma unroll
    for (int cfo = 0; cfo < 16; cfo++) {
      int er = cfo * 16 + l16;
      short8 vb = *(const short8*)&Vb[er * 32 + hi8];
      acc_o[cfo] = __builtin_amdgcn_mfma_f32_16x16x32_bf16(pa, vb, acc_o[cfo], 0, 0, 0);
    }
    __builtin_amdgcn_s_setprio(0);
    __syncthreads();
    cur ^= 1;
  }
  if (half == 1) {
#pragma unroll
    for (int cfo = 0; cfo < 16; cfo++)
#pragma unroll
      for (int j = 0; j < 4; j++)
        Obuf[qb * 4096 + (qd * 4 + j) * 256 + cfo * 16 + l16] = acc_o[cfo][j];
    if (l16 == 0) {
#pragma unroll
      for (int j = 0; j < 4; j++) {
        mst[qb * 16 + qd * 4 + j] = mreg[j];
        lst[qb * 16 + qd * 4 + j] = lreg[j];
      }
    }
  }
  __syncthreads();
  if (half == 0) {
#pragma unroll
    for (int j = 0; j < 4; j++) {
      int r = qd * 4 + j;
      float m1 = mst[qb * 16 + r], l1 = lst[qb * 16 + r];
      float mn = fmaxf(mreg[j], m1);
      float a0 = __expf(mreg[j] - mn), a1 = __expf(m1 - mn);
      float linv = 1.0f / (lreg[j] * a0 + l1 * a1);
      short* yrow = y_bf + (long)(b * L_ + q0 + qb * 16 + r) * KE_ + hk * 256;
#pragma unroll
      for (int cfo = 0; cfo < 16; cfo++) {
        float o1 = Obuf[qb * 4096 + r * 256 + cfo * 16 + l16];
        yrow[cfo * 16 + l16] = f2bf((acc_o[cfo][j] * a0 + o1 * a1) * linv);
      }
    }
  }
}

// ---------------- fused finish ----------------
__global__ __launch_bounds__(256) void finish_k(
    const float* __restrict__ Ptr, const float* __restrict__ Pwo,
    float* __restrict__ xsa, short* __restrict__ xsa_bf,
    short* __restrict__ xsaT_bf) {
  long r = blockIdx.x;
  int b = (int)(r / L_), ll = (int)(r % L_);
  int t = threadIdx.x;
  __shared__ float sm[4];
  long off = r * E_ + t;
  const long ps = (long)BL_ * E_;
  float vd = Ptr[off] + Ptr[ps + off] + Pwo[off] + Pwo[ps + off] +
             Pwo[2 * ps + off] + Pwo[3 * ps + off];
  float s1 = block_sum(vd, sm);
  float s2 = block_sum(vd * vd, sm);
  float mean = s1 * (1.0f / E_);
  float var = (s2 - s1 * mean) * (1.0f / (E_ - 1));
  float vdn = vd / (1.0f + sqrtf(fmaxf(var, 0.f)));
  float u = xsa[off] + STEP_ * vdn;
  s1 = block_sum(u, sm);
  s2 = block_sum(u * u, sm);
  mean = s1 * (1.0f / E_);
  var = (s2 - s1 * mean) * (1.0f / (E_ - 1));
  float xn = u / (1.0f + sqrtf(fmaxf(var, 0.f)));
  xsa[off] = xn;
  short h = f2bf(xn);
  xsa_bf[off] = h;
  xsaT_bf[((long)b * E_ + t) * L_ + ll] = h;
}

// ---------------- fused logits + online LSE ----------------
__global__ __launch_bounds__(256) void lse2_k(
    const short* __restrict__ tmat_bf, const short* __restrict__ embed_bf,
    float* __restrict__ mpart, float* __restrict__ spart) {
  __shared__ short Bs[64 * 256];
  int split = blockIdx.x, rb = blockIdx.y;
  int t = threadIdx.x, w = t >> 6, l = t & 63;
  int l16 = l & 15, qd = l >> 4, hi8 = qd * 8;
  short8 areg[8];
  {
    const short* ar = tmat_bf + (long)(rb * 64 + w * 16 + l16) * E_;
#pragma unroll
    for (int ks = 0; ks < 8; ks++) areg[ks] = *(const short8*)(ar + ks * 32 + hi8);
  }
  float m[4], s[4];
#pragma unroll
  for (int j = 0; j < 4; j++) { m[j] = -1e30f; s[j] = 0.f; }
  long gbase = (long)split * (GCH_ * 64);
  for (int ch = 0; ch < GCH_; ch++) {
    long g0 = gbase + ch * 64;
    __syncthreads();
#pragma unroll
    for (int j = 0; j < 8; j++) {
      int sub = w * 8 + j;
      int r = sub * 2 + (l >> 5);
      int col = ((l & 31) * 8) ^ ((r & 7) << 3);
      gload16(embed_bf + (g0 + r) * E_ + col, &Bs[sub * 512]);
    }
    __syncthreads();
    f32x4 acc[4];
#pragma unroll
    for (int cf = 0; cf < 4; cf++) acc[cf] = {0.f, 0.f, 0.f, 0.f};
    __builtin_amdgcn_s_setprio(1);
#pragma unroll
    for (int ks = 0; ks < 8; ks++) {
#pragma unroll
      for (int cf = 0; cf < 4; cf++) {
        int row = cf * 16 + l16;
        short8 b = *(const short8*)&Bs[(row * 256 + ks * 32 + hi8) ^ ((row & 7) << 3)];
        acc[cf] = __builtin_amdgcn_mfma_f32_16x16x32_bf16(areg[ks], b, acc[cf], 0, 0, 0);
      }
    }
    __builtin_amdgcn_s_setprio(0);
#pragma unroll
    for (int j = 0; j < 4; j++) {
      float vm = fmaxf(fmaxf(acc[0][j], acc[1][j]), fmaxf(acc[2][j], acc[3][j]));
      float mn = fmaxf(m[j], vm);
      s[j] = s[j] * __expf(m[j] - mn) + __expf(acc[0][j] - mn) +
             __expf(acc[1][j] - mn) + __expf(acc[2][j] - mn) +
             __expf(acc[3][j] - mn);
      m[j] = mn;
    }
  }
#pragma unroll
  for (int j = 0; j < 4; j++) {
#pragma unroll
    for (int mask = 1; mask <= 8; mask <<= 1) {
      float mo = __shfl_xor(m[j], mask, 64);
      float so = __shfl_xor(s[j], mask, 64);
      float mn = fmaxf(m[j], mo);
      s[j] = s[j] * __expf(m[j] - mn) + so * __expf(mo - mn);
      m[j] = mn;
    }
    if (l16 == 0) {
      int row = rb * 64 + w * 16 + qd * 4 + j;
      mpart[(long)row * NSPLIT_ + split] = m[j];
      spart[(long)row * NSPLIT_ + split] = s[j];
    }
  }
}

// ---------------- remaining weight conversion (small), one launch ----------
__device__ __forceinline__ void cvt8n_blk(const float* __restrict__ src,
                                          short* __restrict__ dst, int blk,
                                          int nblk, int t) {
#pragma unroll
  for (int r = 0; r < 4; r++) {
    long i = (long)(blk + r * nblk) * 256 + t;
    const float4* s4 = (const float4*)src;
    float4 a = s4[2 * i], b = s4[2 * i + 1];
    short8 o = {f2bf(a.x), f2bf(a.y), f2bf(a.z), f2bf(a.w),
                f2bf(b.x), f2bf(b.y), f2bf(b.z), f2bf(b.w)};
    ((short8*)dst)[i] = o;
  }
}
__device__ __forceinline__ void trans64_blk(const float* __restrict__ src,
                                            short* __restrict__ dst, int bx,
                                            int by, int C, int ldd,
                                            short (*tile)[68], int t) {
  int c0 = bx * 64, r0 = by * 64;
  int tr = t >> 4;
  int tc = (t & 15) * 4;
#pragma unroll
  for (int k = 0; k < 4; k++) {
    int r = tr + k * 16;
    float4 v = *(const float4*)(src + (long)(r0 + r) * C + c0 + tc);
    tile[r][tc + 0] = f2bf(v.x);
    tile[r][tc + 1] = f2bf(v.y);
    tile[r][tc + 2] = f2bf(v.z);
    tile[r][tc + 3] = f2bf(v.w);
  }
  __syncthreads();
#pragma unroll
  for (int j = 0; j < 2; j++) {
    int ch = t + j * 256;
    int rd = ch >> 3;
    int cd = (ch & 7) * 8;
    short8 o;
#pragma unroll
    for (int e = 0; e < 8; e++) o[e] = tile[cd + e][rd];
    *(short8*)(dst + (long)(c0 + rd) * ldd + r0 + cd) = o;
  }
}
// layout (blocks): embed 1000 | wkc 32 | 6x (wcb 8, wcatC 8)=16 | wemT 16 |
// 6x (wtT 16, woT 128, wcatT 16)=160
#define WCVT_BLKS (1000 + 32 + 6 * 16 + 16 + 6 * 160)  // 2104
__global__ __launch_bounds__(256) void wcvt_all_k(
    const float* __restrict__ embed, const float* __restrict__ Wt,
    const float* __restrict__ Wc, const float* __restrict__ Wo,
    const float* __restrict__ Wkc, const float* __restrict__ Wem,
    short* embed_bf, short* wcb, short* wtT, short* woT, short* wcat,
    short* wkc_bf, short* wemT) {
  __shared__ short tile[64][68];
  int blk = blockIdx.x, t = threadIdx.x;
  if (blk < 1000) { cvt8n_blk(embed, embed_bf, blk, 1000, t); return; }
  blk -= 1000;
  if (blk < 32) { cvt8n_blk(Wkc, wkc_bf, blk, 32, t); return; }
  blk -= 32;
  if (blk < 6 * 16) {
    int d = blk / 16;
    int r = blk - d * 16;
    if (r < 8) { cvt8n_blk(Wc + (long)d * E_ * E_, wcb + (long)d * E_ * E_, r, 8, t); return; }
    r -= 8;
    {  // wcat[n][256+k] = Wt[n][k], 4 chunks/thread
      const float* Wt_d = Wt + (long)d * E_ * E_;
      short* wcat_d = wcat + (long)d * E_ * 512;
#pragma unroll
      for (int it = 0; it < 4; it++) {
        long i = (long)(r + it * 8) * 256 + t;
        int n = (int)(i >> 5);
        int kc = (int)(i & 31) * 8;
        float4 a = *(const float4*)(Wt_d + (long)n * E_ + kc);
        float4 b = *(const float4*)(Wt_d + (long)n * E_ + kc + 4);
        short8 o = {f2bf(a.x), f2bf(a.y), f2bf(a.z), f2bf(a.w),
                    f2bf(b.x), f2bf(b.y), f2bf(b.z), f2bf(b.w)};
        *(short8*)(wcat_d + (long)n * 512 + 256 + kc) = o;
      }
      return;
    }
  }
  blk -= 6 * 16;
  if (blk < 16) { trans64_blk(Wem, wemT, blk & 3, blk >> 2, E_, E_, tile, t); return; }
  blk -= 16;
  {
    int d = blk / 160;
    int r = blk - d * 160;
    if (r < 16) {
      trans64_blk(Wt + (long)d * E_ * E_, wtT + (long)d * E_ * E_, r & 3,
                  r >> 2, E_, E_, tile, t);
      return;
    }
    r -= 16;
    if (r < 128) {
      trans64_blk(Wo + (long)d * KE_ * E_, woT + (long)d * E_ * KE_, r & 3,
                  r >> 2, E_, KE_, tile, t);
      return;
    }
    r -= 128;
    trans64_blk(Wc + (long)d * E_ * E_, wcat + (long)d * E_ * 512, r & 3,
                r >> 2, E_, 512, tile, t);
  }
}

// ---------------- small fused kernels ----------------
__global__ __launch_bounds__(256) void embed_init_k(
    const int* __restrict__ masked, const float* __restrict__ embed,
    const float* __restrict__ pos, float* __restrict__ xsa,
    short* __restrict__ xsa_bf, short* __restrict__ xsaT_bf) {
  int bl = blockIdx.x;
  int b = bl / L_, ll = bl % L_;
  int t = threadIdx.x;
  __shared__ float sm[4];
  int tok = masked[bl];
  float v = embed[(long)tok * E_ + t] + pos[(long)ll * E_ + t];
  float s1 = block_sum(v, sm);
  float s2 = block_sum(v * v, sm);
  float mean = s1 * (1.0f / E_);
  float var = (s2 - s1 * mean) * (1.0f / (E_ - 1));
  float xn = v / (1.0f + sqrtf(fmaxf(var, 0.f)));
  xsa[(long)bl * E_ + t] = xn;
  short h = f2bf(xn);
  xsa_bf[(long)bl * E_ + t] = h;
  xsaT_bf[((long)b * E_ + t) * L_ + ll] = h;
}

__global__ __launch_bounds__(256) void gatherbf_k(const short* __restrict__ xsa_bf,
                                                  const int* __restrict__ mask,
                                                  short* __restrict__ lptok_bf) {
  int bm = blockIdx.x;
  int b = bm >> 6;
  int t = threadIdx.x;
  int p = mask[bm];
  lptok_bf[(long)bm * E_ + t] = xsa_bf[((long)b * L_ + p) * E_ + t];
}

__global__ __launch_bounds__(256) void cent_k(
    const short* __restrict__ tmat_bf, const float* __restrict__ embed,
    const int* __restrict__ mask, const int* __restrict__ unmasked,
    const float* __restrict__ mpart, const float* __restrict__ spart,
    float* __restrict__ cent) {
  int bm = blockIdx.x;
  int b = bm >> 6, m = bm & 63;
  int t = threadIdx.x;
  __shared__ float sm[4];
  __shared__ float tlv[KN_];
  int pos = mask[bm];
  int tgt = unmasked[b * L_ + pos];
  float ev = embed[(long)tgt * E_ + t];
  for (int kn = 0; kn < KN_; kn++) {
    long grow = (long)b * (M_ * KN_) + m * KN_ + kn;
    float tv = bf2f(tmat_bf[grow * E_ + t]);
    float dot = block_sum(tv * ev, sm);
    float m2 = (t < NSPLIT_) ? mpart[grow * NSPLIT_ + t] : -1e30f;
    float s2 = (t < NSPLIT_) ? spart[grow * NSPLIT_ + t] : 0.f;
    float Mx = block_max(m2, sm);
    float S = block_sum(s2 * __expf(m2 - Mx), sm);
    if (t == 0) tlv[kn] = dot - (Mx + __logf(S));
  }
  __syncthreads();
  if (t == 0) {
    float mx = fmaxf(fmaxf(tlv[0], tlv[1]), fmaxf(tlv[2], tlv[3]));
    float s = __expf(tlv[0] - mx) + __expf(tlv[1] - mx) + __expf(tlv[2] - mx) +
              __expf(tlv[3] - mx);
    cent[bm] = __logf(s) + mx - 1.3862943611198906f;
  }
}

__global__ __launch_bounds__(256) void loss_k(const float* __restrict__ cent,
                                              const float* __restrict__ summer,
                                              float* __restrict__ out) {
  int t = threadIdx.x;
  int b = t >> 6, m = t & 63;
  float c = cent[b * 64 + m], su = summer[b * 64 + m];
  float num = wsum(c * su);
  float den = wsum(su);
  if (m == 0) out[b] = -num / fmaxf(den, 1.0f);
}

// ---------------- launcher ----------------
extern "C" void kernel_launch(void* const* d_in, const int* in_sizes, int n_in,
                              void* d_out, int out_size, void* d_ws,
                              size_t ws_size, hipStream_t stream) {
  (void)in_sizes; (void)n_in; (void)out_size; (void)ws_size;
  const int* masked = (const int*)d_in[0];
  const int* unmasked = (const int*)d_in[1];
  const int* mask = (const int*)d_in[2];
  const float* summer = (const float*)d_in[3];
  const float* embed = (const float*)d_in[4];
  const float* pos = (const float*)d_in[5];
  const float* Wt = (const float*)d_in[6];
  const float* Wc = (const float*)d_in[7];
  const float* Wq = (const float*)d_in[8];
  const float* Wd = (const float*)d_in[9];
  const float* Wo = (const float*)d_in[10];
  const float* Wkc = (const float*)d_in[11];
  const float* bkc = (const float*)d_in[12];
  const float* Wem = (const float*)d_in[13];
  float* out = (float*)d_out;

  char* p = (char*)d_ws;
  auto take = [&](size_t bytes) {
    char* r = p;
    p += (bytes + 255) & ~(size_t)255;
    return r;
  };
  float* xsa = (float*)take((size_t)BL_ * E_ * 4);
  short* xsa_bf = (short*)take((size_t)BL_ * E_ * 2);
  short* xsaT_bf = (short*)take((size_t)BL_ * E_ * 2);
  short* t_buf = (short*)take((size_t)BL_ * 512 * 2);
  short* q_bf = (short*)take((size_t)BL_ * KE_ * 2);  // reused as xid
  short* y_bf = (short*)take((size_t)BL_ * KE_ * 2);
  float* P_tr = (float*)take((size_t)2 * BL_ * E_ * 4);
  float* P_wo = (float*)take((size_t)4 * BL_ * E_ * 4);
  short* wcb = (short*)take((size_t)D_ * E_ * E_ * 2);
  short* wtT = (short*)take((size_t)D_ * E_ * E_ * 2);
  short* woT = (short*)take((size_t)D_ * E_ * KE_ * 2);
  short* wcat = (short*)take((size_t)D_ * E_ * 512 * 2);
  short* wkc_bf = (short*)take((size_t)KN_ * E_ * E_ * 2);
  short* wemT = (short*)take((size_t)E_ * E_ * 2);
  short* embed_bf = (short*)take((size_t)G_ * E_ * 2);
  short* lptok_bf = (short*)take((size_t)B_ * M_ * E_ * 2);
  short* xx1_bf = (short*)take((size_t)B_ * M_ * KN_ * E_ * 2);
  short* xx2_bf = (short*)take((size_t)B_ * M_ * KN_ * L_ * 2);
  short* xx3_bf = (short*)take((size_t)B_ * M_ * KN_ * E_ * 2);
  short* tmat_bf = (short*)take((size_t)B_ * M_ * KN_ * E_ * 2);
  float* mpart = (float*)take((size_t)1024 * NSPLIT_ * 4);
  float* spart = (float*)take((size_t)1024 * NSPLIT_ * 4);
  float* cent = (float*)take((size_t)B_ * M_ * 4);

  dim3 blk(256);
  wcvt_all_k<<<WCVT_BLKS, blk, 0, stream>>>(embed, Wt, Wc, Wo, Wkc, Wem,
                                            embed_bf, wcb, wtT, woT, wcat,
                                            wkc_bf, wemT);
  embed_init_k<<<BL_, blk, 0, stream>>>(masked, embed, pos, xsa, xsa_bf, xsaT_bf);

  for (int d = 0; d < D_; d++) {
    const float* Wq_d = Wq + (long)d * KE_ * E_;
    const float* Wd_d = Wd + (long)d * KE_ * KE_;
    short* wcb_d = wcb + (long)d * E_ * E_;
    short* wtT_d = wtT + (long)d * E_ * E_;
    short* woT_d = woT + (long)d * E_ * KE_;
    short* wcat_d = wcat + (long)d * E_ * 512;

    tpair_k<<<dim3(4, 32, 2), blk, 0, stream>>>(xsa_bf, wtT_d, wcb_d, t_buf);
    mg64sk_k<<<dim3(4, 32, 2), blk, 0, stream>>>(t_buf, wcat_d, P_tr, 256, 512,
                                                 512, E_, (long)BL_ * E_);
    // q = xsa @ Wq^T  (B = fp32 Wq, converted in staging)
    mg128x64_k<false, true, true><<<512, blk, 0, stream>>>(
        xsa_bf, Wq_d, q_bf, E_, E_, E_, KE_);
    flash3_k<<<dim3(L_ / 64, K_, B_), dim3(512), 0, stream>>>(q_bf, xsa_bf,
                                                              xsaT_bf, y_bf);
    // xid = relu(y @ Wd^T)  (B = fp32 Wd, converted in staging)
    mg128x64_k<true, true, true><<<512, blk, 0, stream>>>(
        y_bf, Wd_d, q_bf, KE_, KE_, KE_, KE_);
    mg64sk_k<<<dim3(4, 32, 4), blk, 0, stream>>>(q_bf, woT_d, P_wo, 512, KE_,
                                                 KE_, E_, (long)BL_ * E_);
    finish_k<<<BL_, blk, 0, stream>>>(P_tr, P_wo, xsa, xsa_bf, xsaT_bf);
  }

  // ---- loss head (bf16 MFMA chain) ----
  gatherbf_k<<<B_ * M_, blk, 0, stream>>>(xsa_bf, mask, lptok_bf);
  mgh_k<true><<<dim3(16, 4, 1), blk, 0, stream>>>(
      lptok_bf, wkc_bf, xx1_bf, bkc, E_, E_, E_, KN_ * E_, 0, 0, 0);
  mgh_k<false><<<dim3(8, 4, B_), blk, 0, stream>>>(
      xx1_bf, xsa_bf, xx2_bf, nullptr, E_, E_, E_, L_,
      (long)M_ * KN_ * E_, (long)L_ * E_, (long)M_ * KN_ * L_);
  mgh_k<false><<<dim3(4, 4, B_), blk, 0, stream>>>(
      xx2_bf, xsaT_bf, xx3_bf, nullptr, L_, L_, L_, E_,
      (long)M_ * KN_ * L_, (long)E_ * L_, (long)M_ * KN_ * E_);
  mgh_k<false><<<dim3(4, 16, 1), blk, 0, stream>>>(
      xx3_bf, wemT, tmat_bf, nullptr, E_, E_, E_, E_, 0, 0, 0);
  lse2_k<<<dim3(NSPLIT_, 16), blk, 0, stream>>>(tmat_bf, embed_bf, mpart, spart);
  cent_k<<<B_ * M_, blk, 0, stream>>>(tmat_bf, embed, mask, unmasked, mpart,
                                      spart, cent);
  loss_k<<<1, blk, 0, stream>>>(cent, summer, out);
}

// Round 12
// 663.031 us; speedup vs baseline: 1.0654x; 1.0654x over previous
//
#include <hip/hip_runtime.h>
#include <math.h>
#include <stdint.h>

#define G_ 32000
#define E_ 256
#define K_ 8
#define D_ 6
#define B_ 4
#define L_ 512
#define M_ 64
#define KN_ 4
#define STEP_ 0.05f
#define BL_ (B_ * L_)   // 2048
#define KE_ (K_ * E_)   // 2048
#define NSPLIT_ 100
#define GCH_ 5

typedef __attribute__((ext_vector_type(8))) short short8;
typedef __attribute__((ext_vector_type(4))) float f32x4;
typedef __attribute__((ext_vector_type(4))) short short4v;

__device__ __forceinline__ short f2bf(float f) {
  unsigned u = __builtin_bit_cast(unsigned, f);
  unsigned r = (u + 0x7fffu + ((u >> 16) & 1u)) >> 16;
  return (short)r;
}
__device__ __forceinline__ float bf2f(short h) {
  return __builtin_bit_cast(float, ((unsigned)(unsigned short)h) << 16);
}

__device__ __forceinline__ void gload16(const void* g, void* l) {
  __builtin_amdgcn_global_load_lds(
      reinterpret_cast<const __attribute__((address_space(1))) void*>(
          reinterpret_cast<uintptr_t>(g)),
      reinterpret_cast<__attribute__((address_space(3))) void*>(
          reinterpret_cast<uintptr_t>(l)),
      16, 0, 0);
}

// ---------------- reduction helpers ----------------
__device__ __forceinline__ float wsum(float v) {
#pragma unroll
  for (int o = 32; o > 0; o >>= 1) v += __shfl_xor(v, o, 64);
  return v;
}
__device__ __forceinline__ float wmaxr(float v) {
#pragma unroll
  for (int o = 32; o > 0; o >>= 1) v = fmaxf(v, __shfl_xor(v, o, 64));
  return v;
}
__device__ __forceinline__ float block_sum(float v, float* sm) {
  v = wsum(v);
  int wid = threadIdx.x >> 6, lane = threadIdx.x & 63;
  if (lane == 0) sm[wid] = v;
  __syncthreads();
  float r = sm[0] + sm[1] + sm[2] + sm[3];
  __syncthreads();
  return r;
}
__device__ __forceinline__ float block_max(float v, float* sm) {
  v = wmaxr(v);
  int wid = threadIdx.x >> 6, lane = threadIdx.x & 63;
  if (lane == 0) sm[wid] = v;
  __syncthreads();
  float r = fmaxf(fmaxf(sm[0], sm[1]), fmaxf(sm[2], sm[3]));
  __syncthreads();
  return r;
}

// ---------------- 128x64 MFMA GEMM ----------------
template <bool RELU, bool OBF>
__global__ __launch_bounds__(256) void mg128x64_k(
    const short* __restrict__ A, const short* __restrict__ B,
    void* __restrict__ Cg, int Kd, int lda, int ldb, int ldc) {
  __shared__ short As[128 * 64];
  __shared__ short Bs[64 * 64];
  int m0 = blockIdx.y * 128, n0 = blockIdx.x * 64;
  int t = threadIdx.x, w = t >> 6, l = t & 63;
  int l16 = l & 15, qd = l >> 4, hi8 = qd * 8;
  int wr_ = w >> 1, wc_ = w & 1;
  int sr = l >> 3;
  int scol = ((l & 7) * 8) ^ (sr << 3);
  f32x4 acc[4][2];
#pragma unroll
  for (int i = 0; i < 4; i++)
#pragma unroll
    for (int j = 0; j < 2; j++) acc[i][j] = {0.f, 0.f, 0.f, 0.f};

  for (int k0 = 0; k0 < Kd; k0 += 64) {
    __syncthreads();
#pragma unroll
    for (int c = 0; c < 4; c++) {
      int sub = w * 4 + c;
      int r = sub * 8 + sr;
      gload16(A + (long)(m0 + r) * lda + k0 + scol, &As[sub * 512]);
    }
#pragma unroll
    for (int c = 0; c < 2; c++) {
      int sub = w * 2 + c;
      int r = sub * 8 + sr;
      gload16(B + (long)(n0 + r) * ldb + k0 + scol, &Bs[sub * 512]);
    }
    __syncthreads();
#pragma unroll
    for (int ks = 0; ks < 2; ks++) {
      short8 af[4], bf[2];
#pragma unroll
      for (int rf = 0; rf < 4; rf++) {
        int row = wr_ * 64 + rf * 16 + l16;
        af[rf] = *(const short8*)&As[(row * 64 + ks * 32 + hi8) ^ ((row & 7) << 3)];
      }
#pragma unroll
      for (int cf = 0; cf < 2; cf++) {
        int row = wc_ * 32 + cf * 16 + l16;
        bf[cf] = *(const short8*)&Bs[(row * 64 + ks * 32 + hi8) ^ ((row & 7) << 3)];
      }
#pragma unroll
      for (int rf = 0; rf < 4; rf++)
#pragma unroll
        for (int cf = 0; cf < 2; cf++)
          acc[rf][cf] = __builtin_amdgcn_mfma_f32_16x16x32_bf16(
              af[rf], bf[cf], acc[rf][cf], 0, 0, 0);
    }
  }
#pragma unroll
  for (int rf = 0; rf < 4; rf++) {
#pragma unroll
    for (int cf = 0; cf < 2; cf++) {
      int col = n0 + wc_ * 32 + cf * 16 + l16;
#pragma unroll
      for (int j = 0; j < 4; j++) {
        int row = m0 + wr_ * 64 + rf * 16 + qd * 4 + j;
        float v = acc[rf][cf][j];
        if (RELU) v = fmaxf(v, 0.f);
        long idx = (long)row * ldc + col;
        if (OBF) ((short*)Cg)[idx] = f2bf(v);
        else ((float*)Cg)[idx] = v;
      }
    }
  }
}

// ---------------- 64x64 MFMA GEMM, split-K to fp32 partials ----------------
__global__ __launch_bounds__(256) void mg64sk_k(
    const short* __restrict__ A, const short* __restrict__ B,
    float* __restrict__ P, int Klen, int lda, int ldb, int ldc, long pstride) {
  __shared__ short As[64 * 64];
  __shared__ short Bs[64 * 64];
  int z = blockIdx.z;
  int kbase = z * Klen;
  int m0 = blockIdx.y * 64, n0 = blockIdx.x * 64;
  int t = threadIdx.x, w = t >> 6, l = t & 63;
  int l16 = l & 15, qd = l >> 4, hi8 = qd * 8;
  int wr_ = w >> 1, wc_ = w & 1;
  int sr = l >> 3;
  int scol = ((l & 7) * 8) ^ (sr << 3);
  f32x4 acc[2][2];
#pragma unroll
  for (int i = 0; i < 2; i++)
#pragma unroll
    for (int j = 0; j < 2; j++) acc[i][j] = {0.f, 0.f, 0.f, 0.f};

  for (int k0 = 0; k0 < Klen; k0 += 64) {
    __syncthreads();
#pragma unroll
    for (int c = 0; c < 2; c++) {
      int sub = w * 2 + c;
      int r = sub * 8 + sr;
      gload16(A + (long)(m0 + r) * lda + kbase + k0 + scol, &As[sub * 512]);
      gload16(B + (long)(n0 + r) * ldb + kbase + k0 + scol, &Bs[sub * 512]);
    }
    __syncthreads();
#pragma unroll
    for (int ks = 0; ks < 2; ks++) {
      short8 af[2], bf[2];
#pragma unroll
      for (int rf = 0; rf < 2; rf++) {
        int row = wr_ * 32 + rf * 16 + l16;
        af[rf] = *(const short8*)&As[(row * 64 + ks * 32 + hi8) ^ ((row & 7) << 3)];
      }
#pragma unroll
      for (int cf = 0; cf < 2; cf++) {
        int row = wc_ * 32 + cf * 16 + l16;
        bf[cf] = *(const short8*)&Bs[(row * 64 + ks * 32 + hi8) ^ ((row & 7) << 3)];
      }
#pragma unroll
      for (int rf = 0; rf < 2; rf++)
#pragma unroll
        for (int cf = 0; cf < 2; cf++)
          acc[rf][cf] = __builtin_amdgcn_mfma_f32_16x16x32_bf16(
              af[rf], bf[cf], acc[rf][cf], 0, 0, 0);
    }
  }
  float* Pz = P + z * pstride;
#pragma unroll
  for (int rf = 0; rf < 2; rf++) {
#pragma unroll
    for (int cf = 0; cf < 2; cf++) {
      int col = n0 + wc_ * 32 + cf * 16 + l16;
#pragma unroll
      for (int j = 0; j < 4; j++) {
        int row = m0 + wr_ * 32 + rf * 16 + qd * 4 + j;
        Pz[(long)row * ldc + col] = acc[rf][cf][j];
      }
    }
  }
}

// ---------------- 64x64 MFMA GEMM, bf16 out, batched, opt bias ----------------
template <bool BIAS>
__global__ __launch_bounds__(256) void mgh_k(
    const short* __restrict__ Ag, const short* __restrict__ Bg,
    short* __restrict__ Cg, const float* __restrict__ bias, int Kd, int lda,
    int ldb, int ldc, long sA, long sB, long sC) {
  __shared__ short As[64 * 64];
  __shared__ short Bs[64 * 64];
  int z = blockIdx.z;
  const short* A = Ag + z * sA;
  const short* B = Bg + z * sB;
  short* C = Cg + z * sC;
  int m0 = blockIdx.y * 64, n0 = blockIdx.x * 64;
  int t = threadIdx.x, w = t >> 6, l = t & 63;
  int l16 = l & 15, qd = l >> 4, hi8 = qd * 8;
  int wr_ = w >> 1, wc_ = w & 1;
  int sr = l >> 3;
  int scol = ((l & 7) * 8) ^ (sr << 3);
  f32x4 acc[2][2];
#pragma unroll
  for (int i = 0; i < 2; i++)
#pragma unroll
    for (int j = 0; j < 2; j++) acc[i][j] = {0.f, 0.f, 0.f, 0.f};

  for (int k0 = 0; k0 < Kd; k0 += 64) {
    __syncthreads();
#pragma unroll
    for (int c = 0; c < 2; c++) {
      int sub = w * 2 + c;
      int r = sub * 8 + sr;
      gload16(A + (long)(m0 + r) * lda + k0 + scol, &As[sub * 512]);
      gload16(B + (long)(n0 + r) * ldb + k0 + scol, &Bs[sub * 512]);
    }
    __syncthreads();
#pragma unroll
    for (int ks = 0; ks < 2; ks++) {
      short8 af[2], bf[2];
#pragma unroll
      for (int rf = 0; rf < 2; rf++) {
        int row = wr_ * 32 + rf * 16 + l16;
        af[rf] = *(const short8*)&As[(row * 64 + ks * 32 + hi8) ^ ((row & 7) << 3)];
      }
#pragma unroll
      for (int cf = 0; cf < 2; cf++) {
        int row = wc_ * 32 + cf * 16 + l16;
        bf[cf] = *(const short8*)&Bs[(row * 64 + ks * 32 + hi8) ^ ((row & 7) << 3)];
      }
#pragma unroll
      for (int rf = 0; rf < 2; rf++)
#pragma unroll
        for (int cf = 0; cf < 2; cf++)
          acc[rf][cf] = __builtin_amdgcn_mfma_f32_16x16x32_bf16(
              af[rf], bf[cf], acc[rf][cf], 0, 0, 0);
    }
  }
#pragma unroll
  for (int rf = 0; rf < 2; rf++) {
#pragma unroll
    for (int cf = 0; cf < 2; cf++) {
      int col = n0 + wc_ * 32 + cf * 16 + l16;
      float bv = BIAS ? bias[col] : 0.f;
#pragma unroll
      for (int j = 0; j < 4; j++) {
        int row = m0 + wr_ * 32 + rf * 16 + qd * 4 + j;
        C[(long)row * ldc + col] = f2bf(acc[rf][cf][j] + bv);
      }
    }
  }
}

// ---------------- transition pair (roll, 64x64 tiles) ----------------
__global__ __launch_bounds__(256) void tpair_k(
    const short* __restrict__ xsa_bf, const short* __restrict__ wtT,
    const short* __restrict__ wcb, short* __restrict__ T) {
  __shared__ short As[64 * 64];
  __shared__ short Bs[64 * 64];
  int z = blockIdx.z;
  const short* Bb = z ? wcb : wtT;
  int rollv = z ? -1 : 1;
  int m0 = blockIdx.y * 64, n0 = blockIdx.x * 64;
  int t = threadIdx.x, w = t >> 6, l = t & 63;
  int l16 = l & 15, qd = l >> 4, hi8 = qd * 8;
  int wr_ = w >> 1, wc_ = w & 1;
  int sr = l >> 3;
  int scol = ((l & 7) * 8) ^ (sr << 3);
  f32x4 acc[2][2];
#pragma unroll
  for (int i = 0; i < 2; i++)
#pragma unroll
    for (int j = 0; j < 2; j++) acc[i][j] = {0.f, 0.f, 0.f, 0.f};
  for (int k0 = 0; k0 < E_; k0 += 64) {
    __syncthreads();
#pragma unroll
    for (int c = 0; c < 2; c++) {
      int sub = w * 2 + c;
      int r = sub * 8 + sr;
      int gr = m0 + r;
      int bb = gr >> 9, pp = gr & (L_ - 1);
      gr = (bb << 9) | ((pp - rollv + L_) & (L_ - 1));
      gload16(xsa_bf + (long)gr * E_ + k0 + scol, &As[sub * 512]);
      gload16(Bb + (long)(n0 + r) * E_ + k0 + scol, &Bs[sub * 512]);
    }
    __syncthreads();
#pragma unroll
    for (int ks = 0; ks < 2; ks++) {
      short8 af[2], bf[2];
#pragma unroll
      for (int rf = 0; rf < 2; rf++) {
        int row = wr_ * 32 + rf * 16 + l16;
        af[rf] = *(const short8*)&As[(row * 64 + ks * 32 + hi8) ^ ((row & 7) << 3)];
      }
#pragma unroll
      for (int cf = 0; cf < 2; cf++) {
        int row = wc_ * 32 + cf * 16 + l16;
        bf[cf] = *(const short8*)&Bs[(row * 64 + ks * 32 + hi8) ^ ((row & 7) << 3)];
      }
#pragma unroll
      for (int rf = 0; rf < 2; rf++)
#pragma unroll
        for (int cf = 0; cf < 2; cf++)
          acc[rf][cf] = __builtin_amdgcn_mfma_f32_16x16x32_bf16(
              af[rf], bf[cf], acc[rf][cf], 0, 0, 0);
    }
  }
#pragma unroll
  for (int rf = 0; rf < 2; rf++) {
#pragma unroll
    for (int cf = 0; cf < 2; cf++) {
      int col = n0 + wc_ * 32 + cf * 16 + l16;
#pragma unroll
      for (int j = 0; j < 4; j++) {
        int row = m0 + wr_ * 32 + rf * 16 + qd * 4 + j;
        T[(long)row * 512 + z * 256 + col] = f2bf(fmaxf(acc[rf][cf][j], 0.f));
      }
    }
  }
}

// ---------------- flash attention v4: fused Q projection + flash ----------------
// grid (L/64, K_, B_), 512 threads. Prologue computes Q = xsa @ Wq^T for this
// (b,hk,q0) tile entirely in LDS, then the kv sweep runs as in v3.
__global__ __launch_bounds__(512, 2) void flash4_k(
    const short* __restrict__ xsa_bf, const short* __restrict__ wq,
    const short* __restrict__ xsaT_bf, short* __restrict__ y_bf) {
  __shared__ short smem[69888];
  float* Obuf = (float*)smem;
  float* mst = (float*)&smem[69632];
  float* lst = mst + 64;
  int q0 = blockIdx.x * 64, hk = blockIdx.y, b = blockIdx.z;
  int t = threadIdx.x, w = t >> 6, l = t & 63;
  int l16 = l & 15, qd = l >> 4, hi8 = qd * 8;
  int qb = w & 3, half = w >> 2;
  const float scale = 0.0625f;

  // ---- prologue: Q tile (64x256) = xsa[q0..q0+64] @ wq[hk*256..]^T ----
  short* Albuf = smem;           // 64x256 bf16 (32KB)
  short* Bqbuf = smem + 16384;   // 64x256 bf16 (32KB)
  short* Qbuf = smem + 32768;    // 64x256 bf16 (32KB)
  {
    const short* asrc = xsa_bf + (long)(b * L_ + q0) * E_;
#pragma unroll
    for (int rep = 0; rep < 4; rep++) {
      int idx = rep * 512 + t;
      int row = idx >> 5;
      int cs = (idx & 31) * 8;
      gload16(asrc + (long)row * E_ + (cs ^ ((row & 7) << 3)), Albuf + (size_t)idx * 8);
    }
  }
  for (int c = 0; c < 4; c++) {
    const short* bsrc = wq + (long)(hk * 256 + c * 64) * E_;
#pragma unroll
    for (int rep = 0; rep < 4; rep++) {
      int idx = rep * 512 + t;
      int row = idx >> 5;
      int cs = (idx & 31) * 8;
      gload16(bsrc + (long)row * E_ + (cs ^ ((row & 7) << 3)), Bqbuf + (size_t)idx * 8);
    }
    __syncthreads();
    f32x4 fq[2];
    fq[0] = {0.f, 0.f, 0.f, 0.f};
    fq[1] = {0.f, 0.f, 0.f, 0.f};
#pragma unroll
    for (int ks = 0; ks < 8; ks++) {
      int ar = qb * 16 + l16;
      short8 a = *(const short8*)&Albuf[(ar * 256 + ks * 32 + hi8) ^ ((ar & 7) << 3)];
#pragma unroll
      for (int cf = 0; cf < 2; cf++) {
        int br = half * 32 + cf * 16 + l16;
        short8 bq = *(const short8*)&Bqbuf[(br * 256 + ks * 32 + hi8) ^ ((br & 7) << 3)];
        fq[cf] = __builtin_amdgcn_mfma_f32_16x16x32_bf16(a, bq, fq[cf], 0, 0, 0);
      }
    }
#pragma unroll
    for (int cf = 0; cf < 2; cf++)
#pragma unroll
      for (int j = 0; j < 4; j++) {
        int qr = qb * 16 + qd * 4 + j;
        int qc = c * 64 + half * 32 + cf * 16 + l16;
        Qbuf[(qr * 256 + qc) ^ ((qr & 7) << 3)] = f2bf(fq[cf][j]);
      }
    __syncthreads();
  }
  short8 qf[8];
  {
    int qr = qb * 16 + l16;
#pragma unroll
    for (int ks = 0; ks < 8; ks++)
      qf[ks] = *(const short8*)&Qbuf[(qr * 256 + ks * 32 + hi8) ^ ((qr & 7) << 3)];
  }
  __syncthreads();

  // ---- kv sweep (identical to v3) ----
  f32x4 acc_o[16];
#pragma unroll
  for (int i = 0; i < 16; i++) acc_o[i] = {0.f, 0.f, 0.f, 0.f};
  float mreg[4], lreg[4];
#pragma unroll
  for (int j = 0; j < 4; j++) { mreg[j] = -1e30f; lreg[j] = 0.f; }

  auto STAGE = [&](int nbuf, int it) {
#pragma unroll
    for (int c = 0; c < 4; c++) {
      int ch = w * 4 + c, hh = ch >> 4, rp = ch & 15;
      int row = rp * 2 + (l >> 5);
      int colsw = ((l & 31) * 8) ^ ((row & 7) << 3);
      gload16(xsa_bf + (long)(b * L_ + hh * 256 + it * 32 + row) * E_ + colsw,
              &smem[(nbuf * 2 + hh) * 8192 + rp * 512]);
    }
#pragma unroll
    for (int c = 0; c < 4; c++) {
      int ch = w * 4 + c, hh = ch >> 4, rg = ch & 15;
      int er = rg * 16 + (l >> 2);
      int col = (l & 3) * 8;
      gload16(xsaT_bf + (long)(b * E_ + er) * L_ + hh * 256 + it * 32 + col,
              &smem[32768 + (nbuf * 2 + hh) * 8192 + rg * 512]);
    }
  };

  STAGE(0, 0);
  __syncthreads();
  int cur = 0;
  for (int it = 0; it < 8; it++) {
    if (it < 7) STAGE(cur ^ 1, it + 1);
    const short* Kb = &smem[(cur * 2 + half) * 8192];
    const short* Vb = &smem[32768 + (cur * 2 + half) * 8192];
    short* Pw = &smem[65536 + w * 512];
    f32x4 s4[2];
    s4[0] = {0.f, 0.f, 0.f, 0.f};
    s4[1] = {0.f, 0.f, 0.f, 0.f};
    __builtin_amdgcn_s_setprio(1);
#pragma unroll
    for (int ks = 0; ks < 8; ks++) {
#pragma unroll
      for (int cf = 0; cf < 2; cf++) {
        int row = cf * 16 + l16;
        short8 kb = *(const short8*)&Kb[row * 256 +
                                        ((ks * 32 + hi8) ^ ((row & 7) << 3))];
        s4[cf] = __builtin_amdgcn_mfma_f32_16x16x32_bf16(qf[ks], kb, s4[cf], 0, 0, 0);
      }
    }
    __builtin_amdgcn_s_setprio(0);
    float alpha[4];
#pragma unroll
    for (int j = 0; j < 4; j++) {
      float v0 = s4[0][j] * scale, v1 = s4[1][j] * scale;
      float rmax = fmaxf(v0, v1);
#pragma unroll
      for (int mk = 1; mk <= 8; mk <<= 1) rmax = fmaxf(rmax, __shfl_xor(rmax, mk, 64));
      float mn = fmaxf(mreg[j], rmax);
      float p0 = __expf(v0 - mn), p1 = __expf(v1 - mn);
      float ps = p0 + p1;
#pragma unroll
      for (int mk = 1; mk <= 8; mk <<= 1) ps += __shfl_xor(ps, mk, 64);
      alpha[j] = __expf(mreg[j] - mn);
      lreg[j] = lreg[j] * alpha[j] + ps;
      mreg[j] = mn;
      int r = qd * 4 + j;
      Pw[r * 32 + l16] = f2bf(p0);
      Pw[r * 32 + 16 + l16] = f2bf(p1);
    }
#pragma unroll
    for (int cfo = 0; cfo < 16; cfo++)
#pragma unroll
      for (int j = 0; j < 4; j++) acc_o[cfo][j] *= alpha[j];
    short8 pa = *(const short8*)&Pw[l16 * 32 + hi8];
    __builtin_amdgcn_s_setprio(1);
#pragma unroll
    for (int cfo = 0; cfo < 16; cfo++) {
      int er = cfo * 16 + l16;
      short8 vb = *(const short8*)&Vb[er * 32 + hi8];
      acc_o[cfo] = __builtin_amdgcn_mfma_f32_16x16x32_bf16(pa, vb, acc_o[cfo], 0, 0, 0);
    }
    __builtin_amdgcn_s_setprio(0);
    __syncthreads();
    cur ^= 1;
  }
  if (half == 1) {
#pragma unroll
    for (int cfo = 0; cfo < 16; cfo++)
#pragma unroll
      for (int j = 0; j < 4; j++)
        Obuf[qb * 4096 + (qd * 4 + j) * 256 + cfo * 16 + l16] = acc_o[cfo][j];
    if (l16 == 0) {
#pragma unroll
      for (int j = 0; j < 4; j++) {
        mst[qb * 16 + qd * 4 + j] = mreg[j];
        lst[qb * 16 + qd * 4 + j] = lreg[j];
      }
    }
  }
  __syncthreads();
  if (half == 0) {
#pragma unroll
    for (int j = 0; j < 4; j++) {
      int r = qd * 4 + j;
      float m1 = mst[qb * 16 + r], l1 = lst[qb * 16 + r];
      float mn = fmaxf(mreg[j], m1);
      float a0 = __expf(mreg[j] - mn), a1 = __expf(m1 - mn);
      float linv = 1.0f / (lreg[j] * a0 + l1 * a1);
      short* yrow = y_bf + (long)(b * L_ + q0 + qb * 16 + r) * KE_ + hk * 256;
#pragma unroll
      for (int cfo = 0; cfo < 16; cfo++) {
        float o1 = Obuf[qb * 4096 + r * 256 + cfo * 16 + l16];
        yrow[cfo * 16 + l16] = f2bf((acc_o[cfo][j] * a0 + o1 * a1) * linv);
      }
    }
  }
}

// ---------------- fused finish ----------------
__global__ __launch_bounds__(256) void finish_k(
    const float* __restrict__ Ptr, const float* __restrict__ Pwo,
    float* __restrict__ xsa, short* __restrict__ xsa_bf,
    short* __restrict__ xsaT_bf) {
  long r = blockIdx.x;
  int b = (int)(r / L_), ll = (int)(r % L_);
  int t = threadIdx.x;
  __shared__ float sm[4];
  long off = r * E_ + t;
  const long ps = (long)BL_ * E_;
  float vd = Ptr[off] + Ptr[ps + off] + Pwo[off] + Pwo[ps + off] +
             Pwo[2 * ps + off] + Pwo[3 * ps + off];
  float s1 = block_sum(vd, sm);
  float s2 = block_sum(vd * vd, sm);
  float mean = s1 * (1.0f / E_);
  float var = (s2 - s1 * mean) * (1.0f / (E_ - 1));
  float vdn = vd / (1.0f + sqrtf(fmaxf(var, 0.f)));
  float u = xsa[off] + STEP_ * vdn;
  s1 = block_sum(u, sm);
  s2 = block_sum(u * u, sm);
  mean = s1 * (1.0f / E_);
  var = (s2 - s1 * mean) * (1.0f / (E_ - 1));
  float xn = u / (1.0f + sqrtf(fmaxf(var, 0.f)));
  xsa[off] = xn;
  short h = f2bf(xn);
  xsa_bf[off] = h;
  xsaT_bf[((long)b * E_ + t) * L_ + ll] = h;
}

// ---------------- fused logits + online LSE ----------------
__global__ __launch_bounds__(256) void lse2_k(
    const short* __restrict__ tmat_bf, const short* __restrict__ embed_bf,
    float* __restrict__ mpart, float* __restrict__ spart) {
  __shared__ short Bs[64 * 256];
  int split = blockIdx.x, rb = blockIdx.y;
  int t = threadIdx.x, w = t >> 6, l = t & 63;
  int l16 = l & 15, qd = l >> 4, hi8 = qd * 8;
  short8 areg[8];
  {
    const short* ar = tmat_bf + (long)(rb * 64 + w * 16 + l16) * E_;
#pragma unroll
    for (int ks = 0; ks < 8; ks++) areg[ks] = *(const short8*)(ar + ks * 32 + hi8);
  }
  float m[4], s[4];
#pragma unroll
  for (int j = 0; j < 4; j++) { m[j] = -1e30f; s[j] = 0.f; }
  long gbase = (long)split * (GCH_ * 64);
  for (int ch = 0; ch < GCH_; ch++) {
    long g0 = gbase + ch * 64;
    __syncthreads();
#pragma unroll
    for (int j = 0; j < 8; j++) {
      int sub = w * 8 + j;
      int r = sub * 2 + (l >> 5);
      int col = ((l & 31) * 8) ^ ((r & 7) << 3);
      gload16(embed_bf + (g0 + r) * E_ + col, &Bs[sub * 512]);
    }
    __syncthreads();
    f32x4 acc[4];
#pragma unroll
    for (int cf = 0; cf < 4; cf++) acc[cf] = {0.f, 0.f, 0.f, 0.f};
    __builtin_amdgcn_s_setprio(1);
#pragma unroll
    for (int ks = 0; ks < 8; ks++) {
#pragma unroll
      for (int cf = 0; cf < 4; cf++) {
        int row = cf * 16 + l16;
        short8 b = *(const short8*)&Bs[(row * 256 + ks * 32 + hi8) ^ ((row & 7) << 3)];
        acc[cf] = __builtin_amdgcn_mfma_f32_16x16x32_bf16(areg[ks], b, acc[cf], 0, 0, 0);
      }
    }
    __builtin_amdgcn_s_setprio(0);
#pragma unroll
    for (int j = 0; j < 4; j++) {
      float vm = fmaxf(fmaxf(acc[0][j], acc[1][j]), fmaxf(acc[2][j], acc[3][j]));
      float mn = fmaxf(m[j], vm);
      s[j] = s[j] * __expf(m[j] - mn) + __expf(acc[0][j] - mn) +
             __expf(acc[1][j] - mn) + __expf(acc[2][j] - mn) +
             __expf(acc[3][j] - mn);
      m[j] = mn;
    }
  }
#pragma unroll
  for (int j = 0; j < 4; j++) {
#pragma unroll
    for (int mask = 1; mask <= 8; mask <<= 1) {
      float mo = __shfl_xor(m[j], mask, 64);
      float so = __shfl_xor(s[j], mask, 64);
      float mn = fmaxf(m[j], mo);
      s[j] = s[j] * __expf(m[j] - mn) + so * __expf(mo - mn);
      m[j] = mn;
    }
    if (l16 == 0) {
      int row = rb * 64 + w * 16 + qd * 4 + j;
      mpart[(long)row * NSPLIT_ + split] = m[j];
      spart[(long)row * NSPLIT_ + split] = s[j];
    }
  }
}

// ---------------- ALL weight conversion, one launch ----------
__device__ __forceinline__ void cvt8n_blk(const float* __restrict__ src,
                                          short* __restrict__ dst, int blk,
                                          int nblk, int t) {
#pragma unroll
  for (int r = 0; r < 4; r++) {
    long i = (long)(blk + r * nblk) * 256 + t;
    const float4* s4 = (const float4*)src;
    float4 a = s4[2 * i], b = s4[2 * i + 1];
    short8 o = {f2bf(a.x), f2bf(a.y), f2bf(a.z), f2bf(a.w),
                f2bf(b.x), f2bf(b.y), f2bf(b.z), f2bf(b.w)};
    ((short8*)dst)[i] = o;
  }
}
__device__ __forceinline__ void trans64_blk(const float* __restrict__ src,
                                            short* __restrict__ dst, int bx,
                                            int by, int C, int ldd,
                                            short (*tile)[68], int t) {
  int c0 = bx * 64, r0 = by * 64;
  int tr = t >> 4;
  int tc = (t & 15) * 4;
#pragma unroll
  for (int k = 0; k < 4; k++) {
    int r = tr + k * 16;
    float4 v = *(const float4*)(src + (long)(r0 + r) * C + c0 + tc);
    tile[r][tc + 0] = f2bf(v.x);
    tile[r][tc + 1] = f2bf(v.y);
    tile[r][tc + 2] = f2bf(v.z);
    tile[r][tc + 3] = f2bf(v.w);
  }
  __syncthreads();
#pragma unroll
  for (int j = 0; j < 2; j++) {
    int ch = t + j * 256;
    int rd = ch >> 3;
    int cd = (ch & 7) * 8;
    short8 o;
#pragma unroll
    for (int e = 0; e < 8; e++) o[e] = tile[cd + e][rd];
    *(short8*)(dst + (long)(c0 + rd) * ldd + r0 + cd) = o;
  }
}
// layout (blocks): embed 1000 | wkc 32 | 6x (wd 512, wq 64, wcb 8, wcatC 8)=592
// | wemT 16 | 6x (wtT 16, woT 128, wcatT 16)=160
#define WCVT_BLKS (1000 + 32 + 6 * 592 + 16 + 6 * 160)  // 5560
__global__ __launch_bounds__(256) void wcvt_all_k(
    const float* __restrict__ embed, const float* __restrict__ Wt,
    const float* __restrict__ Wc, const float* __restrict__ Wq,
    const float* __restrict__ Wd, const float* __restrict__ Wo,
    const float* __restrict__ Wkc, const float* __restrict__ Wem,
    short* embed_bf, short* wcb, short* wq, short* wd, short* wtT, short* woT,
    short* wcat, short* wkc_bf, short* wemT) {
  __shared__ short tile[64][68];
  int blk = blockIdx.x, t = threadIdx.x;
  if (blk < 1000) { cvt8n_blk(embed, embed_bf, blk, 1000, t); return; }
  blk -= 1000;
  if (blk < 32) { cvt8n_blk(Wkc, wkc_bf, blk, 32, t); return; }
  blk -= 32;
  if (blk < 6 * 592) {
    int d = blk / 592;
    int r = blk - d * 592;
    if (r < 512) { cvt8n_blk(Wd + (long)d * KE_ * KE_, wd + (long)d * KE_ * KE_, r, 512, t); return; }
    r -= 512;
    if (r < 64) { cvt8n_blk(Wq + (long)d * KE_ * E_, wq + (long)d * KE_ * E_, r, 64, t); return; }
    r -= 64;
    if (r < 8) { cvt8n_blk(Wc + (long)d * E_ * E_, wcb + (long)d * E_ * E_, r, 8, t); return; }
    r -= 8;
    {
      const float* Wt_d = Wt + (long)d * E_ * E_;
      short* wcat_d = wcat + (long)d * E_ * 512;
#pragma unroll
      for (int it = 0; it < 4; it++) {
        long i = (long)(r + it * 8) * 256 + t;
        int n = (int)(i >> 5);
        int kc = (int)(i & 31) * 8;
        float4 a = *(const float4*)(Wt_d + (long)n * E_ + kc);
        float4 b = *(const float4*)(Wt_d + (long)n * E_ + kc + 4);
        short8 o = {f2bf(a.x), f2bf(a.y), f2bf(a.z), f2bf(a.w),
                    f2bf(b.x), f2bf(b.y), f2bf(b.z), f2bf(b.w)};
        *(short8*)(wcat_d + (long)n * 512 + 256 + kc) = o;
      }
      return;
    }
  }
  blk -= 6 * 592;
  if (blk < 16) { trans64_blk(Wem, wemT, blk & 3, blk >> 2, E_, E_, tile, t); return; }
  blk -= 16;
  {
    int d = blk / 160;
    int r = blk - d * 160;
    if (r < 16) {
      trans64_blk(Wt + (long)d * E_ * E_, wtT + (long)d * E_ * E_, r & 3,
                  r >> 2, E_, E_, tile, t);
      return;
    }
    r -= 16;
    if (r < 128) {
      trans64_blk(Wo + (long)d * KE_ * E_, woT + (long)d * E_ * KE_, r & 3,
                  r >> 2, E_, KE_, tile, t);
      return;
    }
    r -= 128;
    trans64_blk(Wc + (long)d * E_ * E_, wcat + (long)d * E_ * 512, r & 3,
                r >> 2, E_, 512, tile, t);
  }
}

// ---------------- small fused kernels ----------------
__global__ __launch_bounds__(256) void embed_init_k(
    const int* __restrict__ masked, const float* __restrict__ embed,
    const float* __restrict__ pos, float* __restrict__ xsa,
    short* __restrict__ xsa_bf, short* __restrict__ xsaT_bf) {
  int bl = blockIdx.x;
  int b = bl / L_, ll = bl % L_;
  int t = threadIdx.x;
  __shared__ float sm[4];
  int tok = masked[bl];
  float v = embed[(long)tok * E_ + t] + pos[(long)ll * E_ + t];
  float s1 = block_sum(v, sm);
  float s2 = block_sum(v * v, sm);
  float mean = s1 * (1.0f / E_);
  float var = (s2 - s1 * mean) * (1.0f / (E_ - 1));
  float xn = v / (1.0f + sqrtf(fmaxf(var, 0.f)));
  xsa[(long)bl * E_ + t] = xn;
  short h = f2bf(xn);
  xsa_bf[(long)bl * E_ + t] = h;
  xsaT_bf[((long)b * E_ + t) * L_ + ll] = h;
}

__global__ __launch_bounds__(256) void gatherbf_k(const short* __restrict__ xsa_bf,
                                                  const int* __restrict__ mask,
                                                  short* __restrict__ lptok_bf) {
  int bm = blockIdx.x;
  int b = bm >> 6;
  int t = threadIdx.x;
  int p = mask[bm];
  lptok_bf[(long)bm * E_ + t] = xsa_bf[((long)b * L_ + p) * E_ + t];
}

__global__ __launch_bounds__(256) void cent_k(
    const short* __restrict__ tmat_bf, const float* __restrict__ embed,
    const int* __restrict__ mask, const int* __restrict__ unmasked,
    const float* __restrict__ mpart, const float* __restrict__ spart,
    float* __restrict__ cent) {
  int bm = blockIdx.x;
  int b = bm >> 6, m = bm & 63;
  int t = threadIdx.x;
  __shared__ float sm[4];
  __shared__ float tlv[KN_];
  int pos = mask[bm];
  int tgt = unmasked[b * L_ + pos];
  float ev = embed[(long)tgt * E_ + t];
  for (int kn = 0; kn < KN_; kn++) {
    long grow = (long)b * (M_ * KN_) + m * KN_ + kn;
    float tv = bf2f(tmat_bf[grow * E_ + t]);
    float dot = block_sum(tv * ev, sm);
    float m2 = (t < NSPLIT_) ? mpart[grow * NSPLIT_ + t] : -1e30f;
    float s2 = (t < NSPLIT_) ? spart[grow * NSPLIT_ + t] : 0.f;
    float Mx = block_max(m2, sm);
    float S = block_sum(s2 * __expf(m2 - Mx), sm);
    if (t == 0) tlv[kn] = dot - (Mx + __logf(S));
  }
  __syncthreads();
  if (t == 0) {
    float mx = fmaxf(fmaxf(tlv[0], tlv[1]), fmaxf(tlv[2], tlv[3]));
    float s = __expf(tlv[0] - mx) + __expf(tlv[1] - mx) + __expf(tlv[2] - mx) +
              __expf(tlv[3] - mx);
    cent[bm] = __logf(s) + mx - 1.3862943611198906f;
  }
}

__global__ __launch_bounds__(256) void loss_k(const float* __restrict__ cent,
                                              const float* __restrict__ summer,
                                              float* __restrict__ out) {
  int t = threadIdx.x;
  int b = t >> 6, m = t & 63;
  float c = cent[b * 64 + m], su = summer[b * 64 + m];
  float num = wsum(c * su);
  float den = wsum(su);
  if (m == 0) out[b] = -num / fmaxf(den, 1.0f);
}

// ---------------- launcher ----------------
extern "C" void kernel_launch(void* const* d_in, const int* in_sizes, int n_in,
                              void* d_out, int out_size, void* d_ws,
                              size_t ws_size, hipStream_t stream) {
  (void)in_sizes; (void)n_in; (void)out_size; (void)ws_size;
  const int* masked = (const int*)d_in[0];
  const int* unmasked = (const int*)d_in[1];
  const int* mask = (const int*)d_in[2];
  const float* summer = (const float*)d_in[3];
  const float* embed = (const float*)d_in[4];
  const float* pos = (const float*)d_in[5];
  const float* Wt = (const float*)d_in[6];
  const float* Wc = (const float*)d_in[7];
  const float* Wq = (const float*)d_in[8];
  const float* Wd = (const float*)d_in[9];
  const float* Wo = (const float*)d_in[10];
  const float* Wkc = (const float*)d_in[11];
  const float* bkc = (const float*)d_in[12];
  const float* Wem = (const float*)d_in[13];
  float* out = (float*)d_out;

  char* p = (char*)d_ws;
  auto take = [&](size_t bytes) {
    char* r = p;
    p += (bytes + 255) & ~(size_t)255;
    return r;
  };
  float* xsa = (float*)take((size_t)BL_ * E_ * 4);
  short* xsa_bf = (short*)take((size_t)BL_ * E_ * 2);
  short* xsaT_bf = (short*)take((size_t)BL_ * E_ * 2);
  short* t_buf = (short*)take((size_t)BL_ * 512 * 2);
  short* xid_bf = (short*)take((size_t)BL_ * KE_ * 2);
  short* y_bf = (short*)take((size_t)BL_ * KE_ * 2);
  float* P_tr = (float*)take((size_t)2 * BL_ * E_ * 4);
  float* P_wo = (float*)take((size_t)4 * BL_ * E_ * 4);
  short* wcb = (short*)take((size_t)D_ * E_ * E_ * 2);
  short* wtT = (short*)take((size_t)D_ * E_ * E_ * 2);
  short* wq = (short*)take((size_t)D_ * KE_ * E_ * 2);
  short* wd = (short*)take((size_t)D_ * KE_ * KE_ * 2);
  short* woT = (short*)take((size_t)D_ * E_ * KE_ * 2);
  short* wcat = (short*)take((size_t)D_ * E_ * 512 * 2);
  short* wkc_bf = (short*)take((size_t)KN_ * E_ * E_ * 2);
  short* wemT = (short*)take((size_t)E_ * E_ * 2);
  short* embed_bf = (short*)take((size_t)G_ * E_ * 2);
  short* lptok_bf = (short*)take((size_t)B_ * M_ * E_ * 2);
  short* xx1_bf = (short*)take((size_t)B_ * M_ * KN_ * E_ * 2);
  short* xx2_bf = (short*)take((size_t)B_ * M_ * KN_ * L_ * 2);
  short* xx3_bf = (short*)take((size_t)B_ * M_ * KN_ * E_ * 2);
  short* tmat_bf = (short*)take((size_t)B_ * M_ * KN_ * E_ * 2);
  float* mpart = (float*)take((size_t)1024 * NSPLIT_ * 4);
  float* spart = (float*)take((size_t)1024 * NSPLIT_ * 4);
  float* cent = (float*)take((size_t)B_ * M_ * 4);

  dim3 blk(256);
  wcvt_all_k<<<WCVT_BLKS, blk, 0, stream>>>(embed, Wt, Wc, Wq, Wd, Wo, Wkc, Wem,
                                            embed_bf, wcb, wq, wd, wtT, woT,
                                            wcat, wkc_bf, wemT);
  embed_init_k<<<BL_, blk, 0, stream>>>(masked, embed, pos, xsa, xsa_bf, xsaT_bf);

  for (int d = 0; d < D_; d++) {
    short* wcb_d = wcb + (long)d * E_ * E_;
    short* wtT_d = wtT + (long)d * E_ * E_;
    short* wq_d = wq + (long)d * KE_ * E_;
    short* wd_d = wd + (long)d * KE_ * KE_;
    short* woT_d = woT + (long)d * E_ * KE_;
    short* wcat_d = wcat + (long)d * E_ * 512;

    tpair_k<<<dim3(4, 32, 2), blk, 0, stream>>>(xsa_bf, wtT_d, wcb_d, t_buf);
    mg64sk_k<<<dim3(4, 32, 2), blk, 0, stream>>>(t_buf, wcat_d, P_tr, 256, 512,
                                                 512, E_, (long)BL_ * E_);
    // fused Q projection + attention
    flash4_k<<<dim3(L_ / 64, K_, B_), dim3(512), 0, stream>>>(xsa_bf, wq_d,
                                                              xsaT_bf, y_bf);
    // xid = relu(y @ Wd^T)
    mg128x64_k<true, true><<<dim3(32, 16), blk, 0, stream>>>(
        y_bf, wd_d, xid_bf, KE_, KE_, KE_, KE_);
    mg64sk_k<<<dim3(4, 32, 4), blk, 0, stream>>>(xid_bf, woT_d, P_wo, 512, KE_,
                                                 KE_, E_, (long)BL_ * E_);
    finish_k<<<BL_, blk, 0, stream>>>(P_tr, P_wo, xsa, xsa_bf, xsaT_bf);
  }

  // ---- loss head (bf16 MFMA chain) ----
  gatherbf_k<<<B_ * M_, blk, 0, stream>>>(xsa_bf, mask, lptok_bf);
  mgh_k<true><<<dim3(16, 4, 1), blk, 0, stream>>>(
      lptok_bf, wkc_bf, xx1_bf, bkc, E_, E_, E_, KN_ * E_, 0, 0, 0);
  mgh_k<false><<<dim3(8, 4, B_), blk, 0, stream>>>(
      xx1_bf, xsa_bf, xx2_bf, nullptr, E_, E_, E_, L_,
      (long)M_ * KN_ * E_, (long)L_ * E_, (long)M_ * KN_ * L_);
  mgh_k<false><<<dim3(4, 4, B_), blk, 0, stream>>>(
      xx2_bf, xsaT_bf, xx3_bf, nullptr, L_, L_, L_, E_,
      (long)M_ * KN_ * L_, (long)E_ * L_, (long)M_ * KN_ * E_);
  mgh_k<false><<<dim3(4, 16, 1), blk, 0, stream>>>(
      xx3_bf, wemT, tmat_bf, nullptr, E_, E_, E_, E_, 0, 0, 0);
  lse2_k<<<dim3(NSPLIT_, 16), blk, 0, stream>>>(tmat_bf, embed_bf, mpart, spart);
  cent_k<<<B_ * M_, blk, 0, stream>>>(tmat_bf, embed, mask, unmasked, mpart,
                                      spart, cent);
  loss_k<<<1, blk, 0, stream>>>(cent, summer, out);
}